// Round 1
// baseline (17226.724 us; speedup 1.0000x reference)
//
#include <hip/hip_runtime.h>

#define NTHR 512
#define BT   128
#define XS   68          // padded row stride (floats) for 64-wide buffers
#define LDS_FLOATS 39984
#define LDS_BYTES  (LDS_FLOATS * 4)

__device__ __forceinline__ float fsig(float x) {
    // 1/(1+e^-x); inf-safe: e=inf -> rcp(inf)=0; e=0 -> 1
    return __builtin_amdgcn_rcpf(1.0f + __expf(-x));
}
__device__ __forceinline__ float ftanh(float x) {
    // 1 - 2/(1+e^{2x}); inf-safe at both ends
    float e = __expf(2.0f * x);
    return 1.0f - 2.0f * __builtin_amdgcn_rcpf(e + 1.0f);
}

// All indices compile-time after unroll (rule #20: no runtime-indexed reg arrays).
#define CELL(ACC, HH, CC)                                                   \
    _Pragma("unroll")                                                       \
    for (int u = 0; u < 2; ++u) {                                           \
        _Pragma("unroll")                                                   \
        for (int j = 0; j < 8; ++j) {                                       \
            float gi = fsig(ACC[j][0 + u]);                                 \
            float gf = fsig(ACC[j][2 + u]);                                 \
            float gg = ftanh(ACC[j][4 + u]);                                \
            float go = fsig(ACC[j][6 + u]);                                 \
            float cn = gf * CC[u][j] + gi * gg;                             \
            CC[u][j] = cn;                                                  \
            HH[u][j] = go * ftanh(cn);                                      \
        }                                                                   \
    }

extern "C" __global__ void __launch_bounds__(NTHR, 2)
gen_lstm(const float* __restrict__ noise,
         const float* __restrict__ wih0, const float* __restrict__ whh0,
         const float* __restrict__ bih0, const float* __restrict__ bhh0,
         const float* __restrict__ wih1, const float* __restrict__ whh1,
         const float* __restrict__ bih1, const float* __restrict__ bhh1,
         const float* __restrict__ wih2, const float* __restrict__ whh2,
         const float* __restrict__ bih2, const float* __restrict__ bhh2,
         const float* __restrict__ w1g, const float* __restrict__ b1g,
         const float* __restrict__ w2g, const float* __restrict__ b2g,
         const float* __restrict__ w3g, const float* __restrict__ b3g,
         const int* __restrict__ lenp, float* __restrict__ out)
{
    extern __shared__ float lds[];
    float* X   = lds;            // [128][68] activation exchange (also y2buf [128][20])
    float* HBF = lds + 8704;     // [128][68] h_old buffer   (also y1buf [128][36])
    float* WB  = lds + 17408;    // [256][68] staged weight matrix
    float* WI0 = lds + 34816;    // [256][4]  w_ih0 (col3=0)
    float* W1B = lds + 35840;    // [32][68]
    float* W2B = lds + 38016;    // [16][36]
    float* W3B = lds + 38592;    // [3][20]
    float* BS  = lds + 38652;    // [3][256] b_ih+b_hh
    float* B1L = lds + 39420;    // [32]
    float* B2L = lds + 39452;    // [16]
    float* B3L = lds + 39468;    // [4]
    float* XF  = lds + 39472;    // [128][4] feedback x (col3=0)

    const int tid = threadIdx.x;
    const int et  = tid & 15;    // element group 0..15  (elements et+16j)
    const int rt  = tid >> 4;    // row group     0..31  (rows rt+32i)
    const int T   = *lenp;
    const long eg0 = (long)blockIdx.x * BT;

    // ---- one-time resident staging ----
    for (int i = tid; i < 256; i += NTHR) {
        WI0[i * 4 + 0] = wih0[i * 3 + 0];
        WI0[i * 4 + 1] = wih0[i * 3 + 1];
        WI0[i * 4 + 2] = wih0[i * 3 + 2];
        WI0[i * 4 + 3] = 0.f;
    }
    for (int i = tid; i < 768; i += NTHR) {
        int l = i >> 8, r = i & 255;
        const float* bi = (l == 0) ? bih0 : ((l == 1) ? bih1 : bih2);
        const float* bh = (l == 0) ? bhh0 : ((l == 1) ? bhh1 : bhh2);
        BS[i] = bi[r] + bh[r];
    }
    for (int i = tid; i < 2048; i += NTHR)
        W1B[(i >> 6) * XS + (i & 63)] = w1g[i];
    if (tid < 512) W2B[(tid >> 5) * 36 + (tid & 31)] = w2g[tid];
    if (tid < 48)  W3B[(tid >> 4) * 20 + (tid & 15)] = w3g[tid];
    if (tid < 32)  B1L[tid] = b1g[tid];
    if (tid < 16)  B2L[tid] = b2g[tid];
    if (tid < 3)   B3L[tid] = b3g[tid];
    if (tid < BT) {
        XF[tid * 4 + 0] = noise[(eg0 + tid) * 3 + 0];
        XF[tid * 4 + 1] = noise[(eg0 + tid) * 3 + 1];
        XF[tid * 4 + 2] = noise[(eg0 + tid) * 3 + 2];
        XF[tid * 4 + 3] = 0.f;
    }

    // per-thread recurrent state: units {rt, rt+32}, elements {et+16j}
    float h0[2][8], c0[2][8], h1[2][8], c1[2][8], h2[2][8], c2[2][8];
    #pragma unroll
    for (int u = 0; u < 2; ++u)
        #pragma unroll
        for (int j = 0; j < 8; ++j) {
            h0[u][j] = c0[u][j] = 0.f;
            h1[u][j] = c1[u][j] = 0.f;
            h2[u][j] = c2[u][j] = 0.f;
        }

    auto stageW = [&](const float* __restrict__ src) {   // 256x64 -> WB padded
        #pragma unroll
        for (int q = 0; q < 8; ++q) {
            int f = q * NTHR + tid;                      // float4 chunk id
            float4 v = ((const float4*)src)[f];
            *(float4*)&WB[(f >> 4) * XS + (f & 15) * 4] = v;
        }
    };
    auto gemmAcc = [&](const float* __restrict__ act, float (&acc)[8][8]) {
        #pragma unroll 2
        for (int kq = 0; kq < 16; ++kq) {
            float4 xv[8];
            #pragma unroll
            for (int j = 0; j < 8; ++j)
                xv[j] = *(const float4*)&act[(et + 16 * j) * XS + kq * 4];
            #pragma unroll
            for (int i = 0; i < 8; ++i) {
                float4 wv = *(const float4*)&WB[(rt + 32 * i) * XS + kq * 4];
                #pragma unroll
                for (int j = 0; j < 8; ++j) {
                    acc[j][i] = fmaf(xv[j].x, wv.x, acc[j][i]);
                    acc[j][i] = fmaf(xv[j].y, wv.y, acc[j][i]);
                    acc[j][i] = fmaf(xv[j].z, wv.z, acc[j][i]);
                    acc[j][i] = fmaf(xv[j].w, wv.w, acc[j][i]);
                }
            }
        }
    };
    auto initAcc = [&](int l, float (&acc)[8][8]) {
        #pragma unroll
        for (int i = 0; i < 8; ++i) {
            float b = BS[l * 256 + rt + 32 * i];
            #pragma unroll
            for (int j = 0; j < 8; ++j) acc[j][i] = b;
        }
    };
    auto writeH = [&](const float (&h)[2][8], float* __restrict__ buf) {
        #pragma unroll
        for (int u = 0; u < 2; ++u)
            #pragma unroll
            for (int j = 0; j < 8; ++j)
                buf[(et + 16 * j) * XS + rt + 32 * u] = h[u][j];
    };

    __syncthreads();

    for (int t = 0; t < T; ++t) {
        float acc[8][8];

        // ================= layer 0 =================
        initAcc(0, acc);
        {   // x-part: XF (B,3 padded to 4) x WI0
            float4 xv0[8];
            #pragma unroll
            for (int j = 0; j < 8; ++j)
                xv0[j] = *(const float4*)&XF[(et + 16 * j) * 4];
            #pragma unroll
            for (int i = 0; i < 8; ++i) {
                float4 wv = *(const float4*)&WI0[(rt + 32 * i) * 4];
                #pragma unroll
                for (int j = 0; j < 8; ++j) {
                    acc[j][i] = fmaf(xv0[j].x, wv.x, acc[j][i]);
                    acc[j][i] = fmaf(xv0[j].y, wv.y, acc[j][i]);
                    acc[j][i] = fmaf(xv0[j].z, wv.z, acc[j][i]);
                }
            }
        }
        stageW(whh0);
        writeH(h0, HBF);                 // h0_{t-1}
        __syncthreads();                 // B1
        gemmAcc(HBF, acc);
        CELL(acc, h0, c0);               // h0 <- h0_t
        __syncthreads();                 // B2: WB, X free
        writeH(h0, X);                   // X <- h0_t
        stageW(wih1);
        writeH(h1, HBF);                 // h1_{t-1}
        __syncthreads();                 // B3

        // ================= layer 1 =================
        initAcc(1, acc);
        gemmAcc(X, acc);                 // x-part (h0_t)
        __syncthreads();                 // B4: WB free
        stageW(whh1);
        __syncthreads();                 // B5
        gemmAcc(HBF, acc);               // h-part
        CELL(acc, h1, c1);
        __syncthreads();                 // B6
        writeH(h1, X);                   // X <- h1_t
        stageW(wih2);
        writeH(h2, HBF);                 // h2_{t-1}
        __syncthreads();                 // B7

        // ================= layer 2 =================
        initAcc(2, acc);
        gemmAcc(X, acc);
        __syncthreads();                 // B8
        stageW(whh2);
        __syncthreads();                 // B9
        gemmAcc(HBF, acc);
        CELL(acc, h2, c2);
        __syncthreads();                 // B10
        writeH(h2, X);                   // X <- h2_t
        __syncthreads();                 // B11

        // ================= MLP head =================
        {   // y1 = leaky(X @ w1.T + b1): 32 rows, thread row rt, elems et+16j
            float a1[8];
            float bb = B1L[rt];
            #pragma unroll
            for (int j = 0; j < 8; ++j) a1[j] = bb;
            #pragma unroll 2
            for (int kq = 0; kq < 16; ++kq) {
                float4 wv = *(const float4*)&W1B[rt * XS + kq * 4];
                #pragma unroll
                for (int j = 0; j < 8; ++j) {
                    float4 xv = *(const float4*)&X[(et + 16 * j) * XS + kq * 4];
                    a1[j] = fmaf(xv.x, wv.x, a1[j]);
                    a1[j] = fmaf(xv.y, wv.y, a1[j]);
                    a1[j] = fmaf(xv.z, wv.z, a1[j]);
                    a1[j] = fmaf(xv.w, wv.w, a1[j]);
                }
            }
            #pragma unroll
            for (int j = 0; j < 8; ++j) {
                float y = a1[j];
                y = (y >= 0.f) ? y : 0.01f * y;
                HBF[(et + 16 * j) * 36 + rt] = y;    // y1buf
            }
        }
        __syncthreads();                 // B12
        {   // y2 = leaky(y1 @ w2.T + b2): 16 rows; thread: elem tid&127, rows 4*(tid>>7)+m
            int e2 = tid & 127, rg = tid >> 7;
            float a2[4];
            #pragma unroll
            for (int m = 0; m < 4; ++m) a2[m] = B2L[rg * 4 + m];
            #pragma unroll
            for (int kq = 0; kq < 8; ++kq) {
                float4 yv = *(const float4*)&HBF[e2 * 36 + kq * 4];
                #pragma unroll
                for (int m = 0; m < 4; ++m) {
                    float4 wv = *(const float4*)&W2B[(rg * 4 + m) * 36 + kq * 4];
                    a2[m] = fmaf(yv.x, wv.x, a2[m]);
                    a2[m] = fmaf(yv.y, wv.y, a2[m]);
                    a2[m] = fmaf(yv.z, wv.z, a2[m]);
                    a2[m] = fmaf(yv.w, wv.w, a2[m]);
                }
            }
            #pragma unroll
            for (int m = 0; m < 4; ++m) {
                float y = a2[m];
                y = (y >= 0.f) ? y : 0.01f * y;
                X[e2 * 20 + rg * 4 + m] = y;         // y2buf
            }
        }
        __syncthreads();                 // B13
        if (tid < 384) {                 // y3 = leaky(y2 @ w3.T + b3): 3 rows
            int e3 = tid & 127, r3 = tid >> 7;       // r3 0..2
            float a3 = B3L[r3];
            #pragma unroll
            for (int kq = 0; kq < 4; ++kq) {
                float4 yv = *(const float4*)&X[e3 * 20 + kq * 4];
                float4 wv = *(const float4*)&W3B[r3 * 20 + kq * 4];
                a3 = fmaf(yv.x, wv.x, a3);
                a3 = fmaf(yv.y, wv.y, a3);
                a3 = fmaf(yv.z, wv.z, a3);
                a3 = fmaf(yv.w, wv.w, a3);
            }
            float y = (a3 >= 0.f) ? a3 : 0.01f * a3;
            XF[e3 * 4 + r3] = y;                     // feedback x_{t+1}
            out[(size_t)(eg0 + e3) * (3 * (size_t)T) + (size_t)t * 3 + r3] = y;
        }
        __syncthreads();                 // B14 (= B0 of next step)
    }
}

extern "C" void kernel_launch(void* const* d_in, const int* in_sizes, int n_in,
                              void* d_out, int out_size, void* d_ws, size_t ws_size,
                              hipStream_t stream)
{
    const float* noise = (const float*)d_in[0];
    const float* wih0  = (const float*)d_in[1];
    const float* whh0  = (const float*)d_in[2];
    const float* bih0  = (const float*)d_in[3];
    const float* bhh0  = (const float*)d_in[4];
    const float* wih1  = (const float*)d_in[5];
    const float* whh1  = (const float*)d_in[6];
    const float* bih1  = (const float*)d_in[7];
    const float* bhh1  = (const float*)d_in[8];
    const float* wih2  = (const float*)d_in[9];
    const float* whh2  = (const float*)d_in[10];
    const float* bih2  = (const float*)d_in[11];
    const float* bhh2  = (const float*)d_in[12];
    const float* w1g   = (const float*)d_in[13];
    const float* b1g   = (const float*)d_in[14];
    const float* w2g   = (const float*)d_in[15];
    const float* b2g   = (const float*)d_in[16];
    const float* w3g   = (const float*)d_in[17];
    const float* b3g   = (const float*)d_in[18];
    const int*   lenp  = (const int*)d_in[19];
    float* out = (float*)d_out;

    int B = in_sizes[0] / 3;          // 32768
    int grid = B / BT;                // 256 blocks = 1 per CU

    // >64KB dynamic LDS needs the opt-in attribute (idempotent, host-side, capture-safe)
    hipFuncSetAttribute((const void*)gen_lstm,
                        hipFuncAttributeMaxDynamicSharedMemorySize, LDS_BYTES);
    gen_lstm<<<grid, NTHR, LDS_BYTES, stream>>>(
        noise, wih0, whh0, bih0, bhh0, wih1, whh1, bih1, bhh1,
        wih2, whh2, bih2, bhh2, w1g, b1g, w2g, b2g, w3g, b3g, lenp, out);
}

// Round 2
// 8718.153 us; speedup vs baseline: 1.9760x; 1.9760x over previous
//
#include <hip/hip_runtime.h>

typedef __attribute__((ext_vector_type(4))) float  f32x4;
typedef __attribute__((ext_vector_type(8))) short  bf16x8;

#define NTHR 512
#define BT   128

// ---------------- LDS byte map (total 163328 <= 163840) ----------------
// planes: [layer][split] 16384B each: [128 elems][64 units] bf16, XOR-swizzled
#define PLANE(L,S) ((L)*32768 + (S)*16384)
#define QBUF(i)    (98304 + (i)*16384)     // 3 rotating 16KB stage buffers
#define XFB_OFF    147456                  // [128][3] f32 feedback x (1536B)
#define Y1_OFF     148992                  // [128][34] bf16 (8704B)
#define Y2_OFF     157696                  // [128][18] bf16 (4608B)
#define W2L_OFF    162304                  // [16][32] bf16 (1024B)
#define LDS_TOTAL  163328

// frag-ordered split weights: 5 gate mats * 64KB + w1 8KB
__device__ __align__(16) unsigned char g_wsbuf[335872];

__device__ __forceinline__ unsigned short f2bf(float v) {
    unsigned int x = __float_as_uint(v);
    unsigned int r = x + 0x7fffu + ((x >> 16) & 1u);
    return (unsigned short)(r >> 16);
}
__device__ __forceinline__ float bf2f_lo(unsigned int d) { return __uint_as_float(d << 16); }
__device__ __forceinline__ float bf2f_hi(unsigned int d) { return __uint_as_float(d & 0xffff0000u); }

__device__ __forceinline__ float fsig(float x) {
    return __builtin_amdgcn_rcpf(1.0f + __expf(-x));
}
__device__ __forceinline__ float ftanh(float x) {
    float e = __expf(2.0f * x);
    return 1.0f - 2.0f * __builtin_amdgcn_rcpf(e + 1.0f);
}

__device__ __forceinline__ void gload16(const void* g, void* l) {
    __builtin_amdgcn_global_load_lds(
        (const __attribute__((address_space(1))) void*)g,
        (__attribute__((address_space(3))) void*)l, 16, 0, 0);
}

// ---------------- prologue: frag-order + split weights ----------------
__global__ void prep_weights(const float* __restrict__ whh0, const float* __restrict__ wih1,
                             const float* __restrict__ whh1, const float* __restrict__ wih2,
                             const float* __restrict__ whh2, const float* __restrict__ w1g)
{
    int gi = blockIdx.x * 256 + threadIdx.x;
    if (gi < 20480) {
        int m = gi >> 12;           // matrix 0..4
        int rem = gi & 4095;
        int b = rem >> 6, l = rem & 63;
        int s = b & 1, ks = (b >> 1) & 1, g = (b >> 2) & 3, ug = b >> 4;
        int row = g * 64 + ug * 16 + (l & 15);
        int kb  = ks * 32 + (l >> 4) * 8;
        const float* src = (m == 0) ? whh0 : (m == 1) ? wih1 : (m == 2) ? whh1
                         : (m == 3) ? wih2 : whh2;
        unsigned short o[8];
        #pragma unroll
        for (int i = 0; i < 8; ++i) {
            float v = src[row * 64 + kb + i];
            unsigned short hh = f2bf(v);
            if (s) {
                float r2 = v - __uint_as_float((unsigned int)hh << 16);
                hh = f2bf(r2);
            }
            o[i] = hh;
        }
        unsigned char* dst = g_wsbuf + m * 65536 + b * 1024 + l * 16;
        #pragma unroll
        for (int i = 0; i < 8; ++i) ((unsigned short*)dst)[i] = o[i];
    } else if (gi < 20992) {
        int g2 = gi - 20480;
        int b = g2 >> 6, l = g2 & 63;
        int s = b & 1, ks = (b >> 1) & 1, nt = b >> 2;
        int row = nt * 16 + (l & 15);
        int kb  = ks * 32 + (l >> 4) * 8;
        unsigned short o[8];
        #pragma unroll
        for (int i = 0; i < 8; ++i) {
            float v = w1g[row * 64 + kb + i];
            unsigned short hh = f2bf(v);
            if (s) {
                float r2 = v - __uint_as_float((unsigned int)hh << 16);
                hh = f2bf(r2);
            }
            o[i] = hh;
        }
        unsigned char* dst = g_wsbuf + 327680 + b * 1024 + l * 16;
        #pragma unroll
        for (int i = 0; i < 8; ++i) ((unsigned short*)dst)[i] = o[i];
    }
}

// ---------------- phase helpers ----------------
#define PH(N) do { asm volatile("s_waitcnt vmcnt(" #N ") lgkmcnt(0)" ::: "memory"); \
    __builtin_amdgcn_s_barrier(); __builtin_amdgcn_sched_barrier(0); } while (0)
#define PH_NB do { asm volatile("s_waitcnt lgkmcnt(0)" ::: "memory"); \
    __builtin_amdgcn_s_barrier(); __builtin_amdgcn_sched_barrier(0); } while (0)

#define MFMA_(A,B,C) __builtin_amdgcn_mfma_f32_16x16x32_bf16(A, B, C, 0, 0, 0)

#define ISSUE_GATE(m, ks, s, bufi) do { \
    _Pragma("unroll") \
    for (int j_ = 0; j_ < 2; ++j_) { \
        int p_ = wv * 2 + j_; int ug_ = p_ >> 2, g_ = p_ & 3; \
        gload16(g_wsbuf + (m) * 65536 + (((ug_ * 4 + g_) * 2 + (ks)) * 2 + (s)) * 1024 + lane * 16, \
                lds + QBUF(bufi) + (ug_ * 4 + g_) * 1024); \
    } } while (0)

#define ISSUE_W1(bufi) \
    gload16(g_wsbuf + 327680 + wv * 1024 + lane * 16, lds + QBUF(bufi) + wv * 1024)

#define ACC_INIT(L) do { \
    _Pragma("unroll") for (int g_ = 0; g_ < 4; ++g_) { \
        f32x4 t_ = {bg[L][g_], bg[L][g_], bg[L][g_], bg[L][g_]}; \
        _Pragma("unroll") for (int mt_ = 0; mt_ < 4; ++mt_) acc[g_][mt_] = t_; \
    } } while (0)

#define GATE_HI(APL, ks, bufi) do { \
    bf16x8 bh_[4]; \
    _Pragma("unroll") for (int g_ = 0; g_ < 4; ++g_) \
        bh_[g_] = *(const bf16x8*)(lds + QBUF(bufi) + (ug * 4 + g_) * 1024 + lane * 16); \
    _Pragma("unroll") for (int mt_ = 0; mt_ < 4; ++mt_) { \
        int ab_ = (((mbase + mt_ * 16 + l15) * 128 + (ks) * 64 + l4 * 16)) ^ rswz; \
        bf16x8 ah_ = *(const bf16x8*)(lds + PLANE(APL, 0) + ab_); \
        bf16x8 al_ = *(const bf16x8*)(lds + PLANE(APL, 1) + ab_); \
        _Pragma("unroll") for (int g_ = 0; g_ < 4; ++g_) { \
            acc[g_][mt_] = MFMA_(ah_, bh_[g_], acc[g_][mt_]); \
            acc[g_][mt_] = MFMA_(al_, bh_[g_], acc[g_][mt_]); \
        } } } while (0)

#define GATE_LO(APL, ks, bufi) do { \
    bf16x8 bl_[4]; \
    _Pragma("unroll") for (int g_ = 0; g_ < 4; ++g_) \
        bl_[g_] = *(const bf16x8*)(lds + QBUF(bufi) + (ug * 4 + g_) * 1024 + lane * 16); \
    _Pragma("unroll") for (int mt_ = 0; mt_ < 4; ++mt_) { \
        int ab_ = (((mbase + mt_ * 16 + l15) * 128 + (ks) * 64 + l4 * 16)) ^ rswz; \
        bf16x8 ah_ = *(const bf16x8*)(lds + PLANE(APL, 0) + ab_); \
        _Pragma("unroll") for (int g_ = 0; g_ < 4; ++g_) \
            acc[g_][mt_] = MFMA_(ah_, bl_[g_], acc[g_][mt_]); \
    } } while (0)

#define CELLPH(L, CARR) do { \
    PH_NB; \
    _Pragma("unroll") for (int mt_ = 0; mt_ < 4; ++mt_) \
    _Pragma("unroll") for (int r_ = 0; r_ < 4; ++r_) { \
        float gi_ = fsig(acc[0][mt_][r_]); \
        float gf_ = fsig(acc[1][mt_][r_]); \
        float gg_ = ftanh(acc[2][mt_][r_]); \
        float go_ = fsig(acc[3][mt_][r_]); \
        float cn_ = gf_ * CARR[mt_ * 4 + r_] + gi_ * gg_; \
        CARR[mt_ * 4 + r_] = cn_; \
        float hn_ = go_ * ftanh(cn_); \
        int e_ = mbase + mt_ * 16 + l4 * 4 + r_; \
        int wb_ = ((e_ * 128 + u * 2)) ^ ((e_ & 7) << 4); \
        unsigned short hh_ = f2bf(hn_); \
        float hf_ = __uint_as_float((unsigned int)hh_ << 16); \
        unsigned short hl_ = f2bf(hn_ - hf_); \
        *(unsigned short*)(lds + PLANE(L, 0) + wb_) = hh_; \
        *(unsigned short*)(lds + PLANE(L, 1) + wb_) = hl_; \
    } } while (0)

#define XPART do { \
    _Pragma("unroll") for (int mt_ = 0; mt_ < 4; ++mt_) \
    _Pragma("unroll") for (int r_ = 0; r_ < 4; ++r_) { \
        int e_ = mbase + mt_ * 16 + l4 * 4 + r_; \
        const float* xp_ = (const float*)(lds + XFB_OFF + e_ * 12); \
        float x0_ = xp_[0], x1_ = xp_[1], x2_ = xp_[2]; \
        _Pragma("unroll") for (int g_ = 0; g_ < 4; ++g_) \
            acc[g_][mt_][r_] += x0_ * w0r[g_][0] + x1_ * w0r[g_][1] + x2_ * w0r[g_][2]; \
    } } while (0)

#define MLP1 do { \
    _Pragma("unroll") for (int mi_ = 0; mi_ < 2; ++mi_) { \
        int Mt_ = (wv >> 1) + mi_ * 4; \
        f32x4 a1_ = {b1reg, b1reg, b1reg, b1reg}; \
        _Pragma("unroll") for (int ks_ = 0; ks_ < 2; ++ks_) { \
            int ab_ = (((Mt_ * 16 + l15) * 128 + ks_ * 64 + l4 * 16)) ^ rswz; \
            bf16x8 ah_ = *(const bf16x8*)(lds + PLANE(2, 0) + ab_); \
            bf16x8 al_ = *(const bf16x8*)(lds + PLANE(2, 1) + ab_); \
            bf16x8 wh_ = *(const bf16x8*)(lds + QBUF(2) + (((wv & 1) * 2 + ks_) * 2 + 0) * 1024 + lane * 16); \
            bf16x8 wl_ = *(const bf16x8*)(lds + QBUF(2) + (((wv & 1) * 2 + ks_) * 2 + 1) * 1024 + lane * 16); \
            a1_ = MFMA_(ah_, wh_, a1_); \
            a1_ = MFMA_(al_, wh_, a1_); \
            a1_ = MFMA_(ah_, wl_, a1_); \
        } \
        _Pragma("unroll") for (int r_ = 0; r_ < 4; ++r_) { \
            float y_ = a1_[r_]; y_ = (y_ >= 0.f) ? y_ : 0.01f * y_; \
            int e_ = Mt_ * 16 + l4 * 4 + r_; \
            *(unsigned short*)(lds + Y1_OFF + e_ * 68 + (wv & 1) * 32 + l15 * 2) = f2bf(y_); \
        } } } while (0)

#define MLP2 do { \
    int e2_ = tid & 127, rg_ = tid >> 7; \
    float a2_[4] = {b2r[0], b2r[1], b2r[2], b2r[3]}; \
    _Pragma("unroll") for (int kd_ = 0; kd_ < 16; ++kd_) { \
        unsigned int d_ = *(const unsigned int*)(lds + Y1_OFF + e2_ * 68 + kd_ * 4); \
        float v0_ = bf2f_lo(d_), v1_ = bf2f_hi(d_); \
        _Pragma("unroll") for (int m_ = 0; m_ < 4; ++m_) { \
            unsigned int w_ = *(const unsigned int*)(lds + W2L_OFF + ((rg_ * 4 + m_) * 32 + kd_ * 2) * 2); \
            a2_[m_] = fmaf(v0_, bf2f_lo(w_), a2_[m_]); \
            a2_[m_] = fmaf(v1_, bf2f_hi(w_), a2_[m_]); \
        } } \
    _Pragma("unroll") for (int m_ = 0; m_ < 4; ++m_) { \
        float y_ = a2_[m_]; y_ = (y_ >= 0.f) ? y_ : 0.01f * y_; \
        *(unsigned short*)(lds + Y2_OFF + e2_ * 36 + (rg_ * 4 + m_) * 2) = f2bf(y_); \
    } } while (0)

#define MLP3_OUT do { \
    if (tid < 384) { \
        int e3_ = tid & 127, r3_ = tid >> 7; \
        float a3_ = b3r; \
        _Pragma("unroll") for (int kd_ = 0; kd_ < 8; ++kd_) { \
            unsigned int d_ = *(const unsigned int*)(lds + Y2_OFF + e3_ * 36 + kd_ * 4); \
            a3_ = fmaf(bf2f_lo(d_), w3r[kd_ * 2],     a3_); \
            a3_ = fmaf(bf2f_hi(d_), w3r[kd_ * 2 + 1], a3_); \
        } \
        float y_ = (a3_ >= 0.f) ? a3_ : 0.01f * a3_; \
        *(float*)(lds + XFB_OFF + e3_ * 12 + r3_ * 4) = y_; \
        out[(eg0 + e3_) * outs + (long)t * 3 + r3_] = y_; \
    } } while (0)

// ---------------- main persistent kernel ----------------
extern "C" __global__ void __launch_bounds__(NTHR, 2)
lstm_mfma(const float* __restrict__ noise,
          const float* __restrict__ wih0, const float* __restrict__ whh0,
          const float* __restrict__ bih0, const float* __restrict__ bhh0,
          const float* __restrict__ wih1, const float* __restrict__ whh1,
          const float* __restrict__ bih1, const float* __restrict__ bhh1,
          const float* __restrict__ wih2, const float* __restrict__ whh2,
          const float* __restrict__ bih2, const float* __restrict__ bhh2,
          const float* __restrict__ w1g, const float* __restrict__ b1g,
          const float* __restrict__ w2g, const float* __restrict__ b2g,
          const float* __restrict__ w3g, const float* __restrict__ b3g,
          const int* __restrict__ lenp, float* __restrict__ out)
{
    extern __shared__ unsigned char lds[];
    const int tid  = threadIdx.x;
    const int lane = tid & 63;
    const int wv   = tid >> 6;       // wave 0..7
    const int ug   = wv & 3;         // unit group (16 units)
    const int mh   = wv >> 2;        // M half
    const int l15  = lane & 15;
    const int l4   = lane >> 4;      // k-group
    const int u    = ug * 16 + l15;  // unit 0..63
    const int mbase = mh * 64;
    const int rswz  = (lane & 7) << 4;
    const int T = *lenp;
    const long eg0  = (long)blockIdx.x * BT;
    const long outs = 3L * T;

    // ---- per-thread resident registers ----
    float bg[3][4], w0r[4][3];
    #pragma unroll
    for (int g = 0; g < 4; ++g) {
        int r = g * 64 + u;
        bg[0][g] = bih0[r] + bhh0[r];
        bg[1][g] = bih1[r] + bhh1[r];
        bg[2][g] = bih2[r] + bhh2[r];
        #pragma unroll
        for (int k = 0; k < 3; ++k) w0r[g][k] = wih0[r * 3 + k];
    }
    const float b1reg = b1g[(wv & 1) * 16 + l15];
    const int rg = tid >> 7;
    float b2r[4];
    #pragma unroll
    for (int m = 0; m < 4; ++m) b2r[m] = b2g[rg * 4 + m];
    float w3r[16], b3r;
    {
        int rr = (rg < 3) ? rg : 0;
        #pragma unroll
        for (int k = 0; k < 16; ++k) w3r[k] = w3g[rr * 16 + k];
        b3r = b3g[rr];
    }
    float c0[16], c1[16], c2[16];
    #pragma unroll
    for (int i = 0; i < 16; ++i) { c0[i] = 0.f; c1[i] = 0.f; c2[i] = 0.f; }

    // ---- LDS init ----
    for (int i = tid; i < 98304 / 4; i += NTHR) ((unsigned int*)lds)[i] = 0u;  // h planes = 0
    if (tid < BT) {
        #pragma unroll
        for (int k = 0; k < 3; ++k)
            *(float*)(lds + XFB_OFF + tid * 12 + k * 4) = noise[(eg0 + tid) * 3 + k];
    }
    if (tid < 512) *(unsigned short*)(lds + W2L_OFF + tid * 2) = f2bf(w2g[tid]);

    // drain init loads so vmcnt counting is exact, then pre-stage q0,q1
    asm volatile("s_waitcnt vmcnt(0)" ::: "memory");
    ISSUE_GATE(0, 0, 0, 0);   // q0 whh0.hi.k0 -> buf0
    ISSUE_GATE(0, 1, 0, 1);   // q1 whh0.hi.k1 -> buf1

    f32x4 acc[4][4];

    #pragma unroll 1
    for (int t = 0; t < T; ++t) {
        // ---------------- layer 0: gates = wih0*x + whh0*h0 ----------------
        PH(2); ISSUE_GATE(0, 0, 1, 2);           // q2 whh0.lo.k0
        ACC_INIT(0); XPART;
        GATE_HI(0, 0, 0);
        PH(2); ISSUE_GATE(0, 1, 1, 0);           // q3 whh0.lo.k1
        GATE_HI(0, 1, 1);
        PH(2); ISSUE_GATE(1, 0, 0, 1);           // q4 wih1.hi.k0
        GATE_LO(0, 0, 2);
        PH(2); ISSUE_GATE(1, 1, 0, 2);           // q5 wih1.hi.k1
        GATE_LO(0, 1, 0);
        CELLPH(0, c0);                           // h0 -> H0 planes
        // ---------------- layer 1 ----------------
        PH(2); ISSUE_GATE(1, 0, 1, 0);           // q6 wih1.lo.k0
        ACC_INIT(1);
        GATE_HI(0, 0, 1);                        // wih1 * h0new
        PH(2); ISSUE_GATE(1, 1, 1, 1);           // q7 wih1.lo.k1
        GATE_HI(0, 1, 2);
        PH(2); ISSUE_GATE(2, 0, 0, 2);           // q8 whh1.hi.k0
        GATE_LO(0, 0, 0);
        PH(2); ISSUE_GATE(2, 1, 0, 0);           // q9 whh1.hi.k1
        GATE_LO(0, 1, 1);
        PH(2); ISSUE_GATE(2, 0, 1, 1);           // q10 whh1.lo.k0
        GATE_HI(1, 0, 2);                        // whh1 * h1old
        PH(2); ISSUE_GATE(2, 1, 1, 2);           // q11 whh1.lo.k1
        GATE_HI(1, 1, 0);
        PH(2); ISSUE_GATE(3, 0, 0, 0);           // q12 wih2.hi.k0
        GATE_LO(1, 0, 1);
        PH(2); ISSUE_GATE(3, 1, 0, 1);           // q13 wih2.hi.k1
        GATE_LO(1, 1, 2);
        CELLPH(1, c1);                           // h1 -> H1 planes
        // ---------------- layer 2 ----------------
        PH(2); ISSUE_GATE(3, 0, 1, 2);           // q14 wih2.lo.k0
        ACC_INIT(2);
        GATE_HI(1, 0, 0);                        // wih2 * h1new
        PH(2); ISSUE_GATE(3, 1, 1, 0);           // q15 wih2.lo.k1
        GATE_HI(1, 1, 1);
        PH(2); ISSUE_GATE(4, 0, 0, 1);           // q16 whh2.hi.k0
        GATE_LO(1, 0, 2);
        PH(2); ISSUE_GATE(4, 1, 0, 2);           // q17 whh2.hi.k1
        GATE_LO(1, 1, 0);
        PH(2); ISSUE_GATE(4, 0, 1, 0);           // q18 whh2.lo.k0
        GATE_HI(2, 0, 1);                        // whh2 * h2old
        PH(2); ISSUE_GATE(4, 1, 1, 1);           // q19 whh2.lo.k1
        GATE_HI(2, 1, 2);
        PH(2); ISSUE_W1(2);                      // q20 w1 frags
        GATE_LO(2, 0, 0);
        PH(1); ISSUE_GATE(0, 0, 0, 0);           // q0' (next step) whh0.hi.k0
        GATE_LO(2, 1, 1);
        CELLPH(2, c2);                           // h2 -> H2 planes
        // ---------------- MLP head ----------------
        PH(2); ISSUE_GATE(0, 1, 0, 1);           // q1' (next step) whh0.hi.k1
        MLP1;                                    // y1 via MFMA (A=H2 planes, B=w1 frags)
        PH_NB;
        MLP2;                                    // y2 VALU (y1 bf16, w2 LDS bf16)
        PH_NB;
        MLP3_OUT;                                // y3 -> out + feedback x
        asm volatile("s_waitcnt vmcnt(0) lgkmcnt(0)" ::: "memory");
        __builtin_amdgcn_s_barrier();
        __builtin_amdgcn_sched_barrier(0);
    }
}

extern "C" void kernel_launch(void* const* d_in, const int* in_sizes, int n_in,
                              void* d_out, int out_size, void* d_ws, size_t ws_size,
                              hipStream_t stream)
{
    const float* noise = (const float*)d_in[0];
    const float* wih0  = (const float*)d_in[1];
    const float* whh0  = (const float*)d_in[2];
    const float* bih0  = (const float*)d_in[3];
    const float* bhh0  = (const float*)d_in[4];
    const float* wih1  = (const float*)d_in[5];
    const float* whh1  = (const float*)d_in[6];
    const float* bih1  = (const float*)d_in[7];
    const float* bhh1  = (const float*)d_in[8];
    const float* wih2  = (const float*)d_in[9];
    const float* whh2  = (const float*)d_in[10];
    const float* bih2  = (const float*)d_in[11];
    const float* bhh2  = (const float*)d_in[12];
    const float* w1g   = (const float*)d_in[13];
    const float* b1g   = (const float*)d_in[14];
    const float* w2g   = (const float*)d_in[15];
    const float* b2g   = (const float*)d_in[16];
    const float* w3g   = (const float*)d_in[17];
    const float* b3g   = (const float*)d_in[18];
    const int*   lenp  = (const int*)d_in[19];
    float* out = (float*)d_out;

    int B = in_sizes[0] / 3;              // 32768
    int grid = B / BT;                    // 256 blocks = 1 per CU

    prep_weights<<<82, 256, 0, stream>>>(whh0, wih1, whh1, wih2, whh2, w1g);

    hipFuncSetAttribute((const void*)lstm_mfma,
                        hipFuncAttributeMaxDynamicSharedMemorySize, LDS_TOTAL);
    lstm_mfma<<<grid, NTHR, LDS_TOTAL, stream>>>(
        noise, wih0, whh0, bih0, bhh0, wih1, whh1, bih1, bhh1,
        wih2, whh2, bih2, bhh2, w1g, b1g, w2g, b2g, w3g, b3g, lenp, out);
}

// Round 3
// 6768.731 us; speedup vs baseline: 2.5450x; 1.2880x over previous
//
#include <hip/hip_runtime.h>

typedef __attribute__((ext_vector_type(4))) float  f32x4;
typedef __attribute__((ext_vector_type(8))) short  bf16x8;

#define NTHR 512
#define BT   128

// ---------------- LDS byte map (total 162816 <= 163840) ----------------
// planes: [layer][split] 16384B each: [128 elems][64 units] bf16, XOR-swizzled
#define PLANE(L,S) ((L)*32768 + (S)*16384)
#define QBUF(i)    (98304 + (i)*16384)     // 2 rotating 16KB stage buffers
#define XFB_OFF    131072                  // [128][3] f32 feedback x (1536B)
#define Y1_OFF     132608                  // [128][34] bf16 (8704B)
#define Y2_OFF     141312                  // [128][18] bf16 (4608B)
#define W2L_OFF    145920                  // [16][32] bf16 (1024B)
#define BGL_OFF    146944                  // [3][256] f32 bias sums (3072B)
#define B1L_OFF    150016                  // [32] f32
#define B2L_OFF    150144                  // [16] f32
#define B3L_OFF    150208                  // [4] f32
#define W3L_OFF    150224                  // [3][16] f32 (192B)
#define OUT_OFF    150528                  // [128][24] f32 out ring (12288B)
#define LDS_TOTAL  162816

// frag-ordered split weights: 5 gate mats * 64KB + w1 8KB
__device__ __align__(16) unsigned char g_wsbuf[335872];

__device__ __forceinline__ unsigned short f2bf(float v) {
    unsigned int x = __float_as_uint(v);
    unsigned int r = x + 0x7fffu + ((x >> 16) & 1u);
    return (unsigned short)(r >> 16);
}
__device__ __forceinline__ float bf2f_lo(unsigned int d) { return __uint_as_float(d << 16); }
__device__ __forceinline__ float bf2f_hi(unsigned int d) { return __uint_as_float(d & 0xffff0000u); }

__device__ __forceinline__ float fsig(float x) {
    return __builtin_amdgcn_rcpf(1.0f + __expf(-x));
}
__device__ __forceinline__ float ftanh(float x) {
    float e = __expf(2.0f * x);
    return 1.0f - 2.0f * __builtin_amdgcn_rcpf(e + 1.0f);
}

// ---------------- prologue: frag-order + split weights (unchanged layout) ----------------
__global__ void prep_weights(const float* __restrict__ whh0, const float* __restrict__ wih1,
                             const float* __restrict__ whh1, const float* __restrict__ wih2,
                             const float* __restrict__ whh2, const float* __restrict__ w1g)
{
    int gi = blockIdx.x * 256 + threadIdx.x;
    if (gi < 20480) {
        int m = gi >> 12;
        int rem = gi & 4095;
        int b = rem >> 6, l = rem & 63;
        int s = b & 1, ks = (b >> 1) & 1, g = (b >> 2) & 3, ug = b >> 4;
        int row = g * 64 + ug * 16 + (l & 15);
        int kb  = ks * 32 + (l >> 4) * 8;
        const float* src = (m == 0) ? whh0 : (m == 1) ? wih1 : (m == 2) ? whh1
                         : (m == 3) ? wih2 : whh2;
        unsigned short o[8];
        #pragma unroll
        for (int i = 0; i < 8; ++i) {
            float v = src[row * 64 + kb + i];
            unsigned short hh = f2bf(v);
            if (s) {
                float r2 = v - __uint_as_float((unsigned int)hh << 16);
                hh = f2bf(r2);
            }
            o[i] = hh;
        }
        unsigned char* dst = g_wsbuf + m * 65536 + b * 1024 + l * 16;
        #pragma unroll
        for (int i = 0; i < 8; ++i) ((unsigned short*)dst)[i] = o[i];
    } else if (gi < 20992) {
        int g2 = gi - 20480;
        int b = g2 >> 6, l = g2 & 63;
        int s = b & 1, ks = (b >> 1) & 1, nt = b >> 2;
        int row = nt * 16 + (l & 15);
        int kb  = ks * 32 + (l >> 4) * 8;
        unsigned short o[8];
        #pragma unroll
        for (int i = 0; i < 8; ++i) {
            float v = w1g[row * 64 + kb + i];
            unsigned short hh = f2bf(v);
            if (s) {
                float r2 = v - __uint_as_float((unsigned int)hh << 16);
                hh = f2bf(r2);
            }
            o[i] = hh;
        }
        unsigned char* dst = g_wsbuf + 327680 + b * 1024 + l * 16;
        #pragma unroll
        for (int i = 0; i < 8; ++i) ((unsigned short*)dst)[i] = o[i];
    }
}

#define MFMA_(A,B,C) __builtin_amdgcn_mfma_f32_16x16x32_bf16(A, B, C, 0, 0, 0)

// reg-staged quarter: load (issue-early) and commit (write-late)
#define LOADQ(m, ks, s, R0, R1) do { \
    R0 = *(const bf16x8*)(g_wsbuf + (m) * 65536 + (((wv * 2 + 0) * 2 + (ks)) * 2 + (s)) * 1024 + lane * 16); \
    R1 = *(const bf16x8*)(g_wsbuf + (m) * 65536 + (((wv * 2 + 1) * 2 + (ks)) * 2 + (s)) * 1024 + lane * 16); \
    } while (0)
#define COMMITQ(R0, R1, bufi) do { \
    *(bf16x8*)(lds + QBUF(bufi) + (wv * 2 + 0) * 1024 + lane * 16) = R0; \
    *(bf16x8*)(lds + QBUF(bufi) + (wv * 2 + 1) * 1024 + lane * 16) = R1; \
    } while (0)
#define LOADW1(R0) \
    R0 = *(const bf16x8*)(g_wsbuf + 327680 + wv * 1024 + lane * 16)
#define COMMITW1(R0, bufi) \
    *(bf16x8*)(lds + QBUF(bufi) + wv * 1024 + lane * 16) = R0

#define ACC_INIT(L) do { \
    _Pragma("unroll") for (int g_ = 0; g_ < 4; ++g_) { \
        float b_ = *(const float*)(lds + BGL_OFF + ((L) * 256 + g_ * 64 + u) * 4); \
        f32x4 t_ = {b_, b_, b_, b_}; \
        _Pragma("unroll") for (int mt_ = 0; mt_ < 4; ++mt_) acc[g_][mt_] = t_; \
    } } while (0)

#define GATE_HI(APL, ks, bufi) do { \
    bf16x8 bh_[4]; \
    _Pragma("unroll") for (int g_ = 0; g_ < 4; ++g_) \
        bh_[g_] = *(const bf16x8*)(lds + QBUF(bufi) + (ug * 4 + g_) * 1024 + lane * 16); \
    _Pragma("unroll") for (int mt_ = 0; mt_ < 4; ++mt_) { \
        int ab_ = (((mbase + mt_ * 16 + l15) * 128 + (ks) * 64 + l4 * 16)) ^ rswz; \
        bf16x8 ah_ = *(const bf16x8*)(lds + PLANE(APL, 0) + ab_); \
        bf16x8 al_ = *(const bf16x8*)(lds + PLANE(APL, 1) + ab_); \
        _Pragma("unroll") for (int g_ = 0; g_ < 4; ++g_) { \
            acc[g_][mt_] = MFMA_(ah_, bh_[g_], acc[g_][mt_]); \
            acc[g_][mt_] = MFMA_(al_, bh_[g_], acc[g_][mt_]); \
        } } } while (0)

#define GATE_LO(APL, ks, bufi) do { \
    bf16x8 bl_[4]; \
    _Pragma("unroll") for (int g_ = 0; g_ < 4; ++g_) \
        bl_[g_] = *(const bf16x8*)(lds + QBUF(bufi) + (ug * 4 + g_) * 1024 + lane * 16); \
    _Pragma("unroll") for (int mt_ = 0; mt_ < 4; ++mt_) { \
        int ab_ = (((mbase + mt_ * 16 + l15) * 128 + (ks) * 64 + l4 * 16)) ^ rswz; \
        bf16x8 ah_ = *(const bf16x8*)(lds + PLANE(APL, 0) + ab_); \
        _Pragma("unroll") for (int g_ = 0; g_ < 4; ++g_) \
            acc[g_][mt_] = MFMA_(ah_, bl_[g_], acc[g_][mt_]); \
    } } while (0)

#define CELLW(L, CARR) do { \
    _Pragma("unroll") for (int mt_ = 0; mt_ < 4; ++mt_) \
    _Pragma("unroll") for (int r_ = 0; r_ < 4; ++r_) { \
        float gi_ = fsig(acc[0][mt_][r_]); \
        float gf_ = fsig(acc[1][mt_][r_]); \
        float gg_ = ftanh(acc[2][mt_][r_]); \
        float go_ = fsig(acc[3][mt_][r_]); \
        float cn_ = gf_ * CARR[mt_ * 4 + r_] + gi_ * gg_; \
        CARR[mt_ * 4 + r_] = cn_; \
        float hn_ = go_ * ftanh(cn_); \
        int e_ = mbase + mt_ * 16 + l4 * 4 + r_; \
        int wb_ = ((e_ * 128 + u * 2)) ^ ((e_ & 7) << 4); \
        unsigned short hh_ = f2bf(hn_); \
        float hf_ = __uint_as_float((unsigned int)hh_ << 16); \
        unsigned short hl_ = f2bf(hn_ - hf_); \
        *(unsigned short*)(lds + PLANE(L, 0) + wb_) = hh_; \
        *(unsigned short*)(lds + PLANE(L, 1) + wb_) = hl_; \
    } } while (0)

#define XPART do { \
    _Pragma("unroll") for (int mt_ = 0; mt_ < 4; ++mt_) \
    _Pragma("unroll") for (int r_ = 0; r_ < 4; ++r_) { \
        int e_ = mbase + mt_ * 16 + l4 * 4 + r_; \
        const float* xp_ = (const float*)(lds + XFB_OFF + e_ * 12); \
        float x0_ = xp_[0], x1_ = xp_[1], x2_ = xp_[2]; \
        _Pragma("unroll") for (int g_ = 0; g_ < 4; ++g_) \
            acc[g_][mt_][r_] += x0_ * w0r[g_][0] + x1_ * w0r[g_][1] + x2_ * w0r[g_][2]; \
    } } while (0)

#define MLP1 do { \
    float b1_ = *(const float*)(lds + B1L_OFF + ((wv & 1) * 16 + l15) * 4); \
    _Pragma("unroll") for (int mi_ = 0; mi_ < 2; ++mi_) { \
        int Mt_ = (wv >> 1) + mi_ * 4; \
        f32x4 a1_ = {b1_, b1_, b1_, b1_}; \
        _Pragma("unroll") for (int ks_ = 0; ks_ < 2; ++ks_) { \
            int ab_ = (((Mt_ * 16 + l15) * 128 + ks_ * 64 + l4 * 16)) ^ rswz; \
            bf16x8 ah_ = *(const bf16x8*)(lds + PLANE(2, 0) + ab_); \
            bf16x8 al_ = *(const bf16x8*)(lds + PLANE(2, 1) + ab_); \
            bf16x8 wh_ = *(const bf16x8*)(lds + QBUF(0) + (((wv & 1) * 2 + ks_) * 2 + 0) * 1024 + lane * 16); \
            bf16x8 wl_ = *(const bf16x8*)(lds + QBUF(0) + (((wv & 1) * 2 + ks_) * 2 + 1) * 1024 + lane * 16); \
            a1_ = MFMA_(ah_, wh_, a1_); \
            a1_ = MFMA_(al_, wh_, a1_); \
            a1_ = MFMA_(ah_, wl_, a1_); \
        } \
        _Pragma("unroll") for (int r_ = 0; r_ < 4; ++r_) { \
            float y_ = a1_[r_]; y_ = (y_ >= 0.f) ? y_ : 0.01f * y_; \
            int e_ = Mt_ * 16 + l4 * 4 + r_; \
            *(unsigned short*)(lds + Y1_OFF + e_ * 68 + (wv & 1) * 32 + l15 * 2) = f2bf(y_); \
        } } } while (0)

#define MLP2 do { \
    int e2_ = tid & 127, rg_ = tid >> 7; \
    float a2_[4]; \
    _Pragma("unroll") for (int m_ = 0; m_ < 4; ++m_) \
        a2_[m_] = *(const float*)(lds + B2L_OFF + (rg_ * 4 + m_) * 4); \
    _Pragma("unroll") for (int kd_ = 0; kd_ < 16; ++kd_) { \
        unsigned int d_ = *(const unsigned int*)(lds + Y1_OFF + e2_ * 68 + kd_ * 4); \
        float v0_ = bf2f_lo(d_), v1_ = bf2f_hi(d_); \
        _Pragma("unroll") for (int m_ = 0; m_ < 4; ++m_) { \
            unsigned int w_ = *(const unsigned int*)(lds + W2L_OFF + ((rg_ * 4 + m_) * 32 + kd_ * 2) * 2); \
            a2_[m_] = fmaf(v0_, bf2f_lo(w_), a2_[m_]); \
            a2_[m_] = fmaf(v1_, bf2f_hi(w_), a2_[m_]); \
        } } \
    _Pragma("unroll") for (int m_ = 0; m_ < 4; ++m_) { \
        float y_ = a2_[m_]; y_ = (y_ >= 0.f) ? y_ : 0.01f * y_; \
        *(unsigned short*)(lds + Y2_OFF + e2_ * 36 + (rg_ * 4 + m_) * 2) = f2bf(y_); \
    } } while (0)

#define MLP3_OUT do { \
    if (tid < 384) { \
        int e3_ = tid & 127, r3_ = tid >> 7; \
        float a3_ = *(const float*)(lds + B3L_OFF + r3_ * 4); \
        _Pragma("unroll") for (int kd_ = 0; kd_ < 8; ++kd_) { \
            unsigned int d_ = *(const unsigned int*)(lds + Y2_OFF + e3_ * 36 + kd_ * 4); \
            a3_ = fmaf(bf2f_lo(d_), *(const float*)(lds + W3L_OFF + (r3_ * 16 + kd_ * 2) * 4),     a3_); \
            a3_ = fmaf(bf2f_hi(d_), *(const float*)(lds + W3L_OFF + (r3_ * 16 + kd_ * 2 + 1) * 4), a3_); \
        } \
        float y_ = (a3_ >= 0.f) ? a3_ : 0.01f * a3_; \
        *(float*)(lds + XFB_OFF + e3_ * 12 + r3_ * 4) = y_; \
        *(float*)(lds + OUT_OFF + e3_ * 96 + (t & 7) * 12 + r3_ * 4) = y_; \
    } } while (0)

// ---------------- main persistent kernel ----------------
extern "C" __global__ void __launch_bounds__(NTHR, 2)
lstm_mfma(const float* __restrict__ noise,
          const float* __restrict__ wih0, const float* __restrict__ whh0,
          const float* __restrict__ bih0, const float* __restrict__ bhh0,
          const float* __restrict__ wih1, const float* __restrict__ whh1,
          const float* __restrict__ bih1, const float* __restrict__ bhh1,
          const float* __restrict__ wih2, const float* __restrict__ whh2,
          const float* __restrict__ bih2, const float* __restrict__ bhh2,
          const float* __restrict__ w1g, const float* __restrict__ b1g,
          const float* __restrict__ w2g, const float* __restrict__ b2g,
          const float* __restrict__ w3g, const float* __restrict__ b3g,
          const int* __restrict__ lenp, float* __restrict__ out)
{
    extern __shared__ unsigned char lds[];
    const int tid  = threadIdx.x;
    const int lane = tid & 63;
    const int wv   = tid >> 6;       // wave 0..7
    const int ug   = wv & 3;         // unit group (16 units)
    const int mh   = wv >> 2;        // M half
    const int l15  = lane & 15;
    const int l4   = lane >> 4;      // k-group
    const int u    = ug * 16 + l15;  // unit 0..63
    const int mbase = mh * 64;
    const int rswz  = (lane & 7) << 4;
    const int T = *lenp;
    const long eg0  = (long)blockIdx.x * BT;
    const long outs = 3L * T;

    // ---- per-thread resident registers (minimal; rest in LDS) ----
    float w0r[4][3];
    #pragma unroll
    for (int g = 0; g < 4; ++g) {
        int r = g * 64 + u;
        #pragma unroll
        for (int k = 0; k < 3; ++k) w0r[g][k] = wih0[r * 3 + k];
    }
    float c0[16], c1[16], c2[16];
    #pragma unroll
    for (int i = 0; i < 16; ++i) { c0[i] = 0.f; c1[i] = 0.f; c2[i] = 0.f; }

    // ---- LDS init ----
    for (int i = tid; i < 98304 / 4; i += NTHR) ((unsigned int*)lds)[i] = 0u;  // h planes = 0
    if (tid < BT) {
        #pragma unroll
        for (int k = 0; k < 3; ++k)
            *(float*)(lds + XFB_OFF + tid * 12 + k * 4) = noise[(eg0 + tid) * 3 + k];
    }
    if (tid < 512) *(unsigned short*)(lds + W2L_OFF + tid * 2) = f2bf(w2g[tid]);
    for (int i = tid; i < 768; i += NTHR) {            // bias sums
        int l = i >> 8, r = i & 255;
        const float* bi = (l == 0) ? bih0 : ((l == 1) ? bih1 : bih2);
        const float* bh = (l == 0) ? bhh0 : ((l == 1) ? bhh1 : bhh2);
        *(float*)(lds + BGL_OFF + i * 4) = bi[r] + bh[r];
    }
    if (tid < 32) *(float*)(lds + B1L_OFF + tid * 4) = b1g[tid];
    if (tid < 16) *(float*)(lds + B2L_OFF + tid * 4) = b2g[tid];
    if (tid < 3)  *(float*)(lds + B3L_OFF + tid * 4) = b3g[tid];
    if (tid < 48) *(float*)(lds + W3L_OFF + tid * 4) = w3g[tid];

    // staging registers (double-buffered quarters)
    bf16x8 RA0, RA1, RB0, RB1;

    // warmup: q0 = whh0(ks0,s0), q1 = whh0(ks1,s0)
    LOADQ(0, 0, 0, RA0, RA1);
    LOADQ(0, 1, 0, RB0, RB1);
    __syncthreads();                 // init LDS visible
    COMMITQ(RA0, RA1, 0);
    COMMITQ(RB0, RB1, 1);
    __syncthreads();                 // buf0=q0, buf1=q1 ready

    f32x4 acc[4][4];

    #pragma unroll 1
    for (int t = 0; t < T; ++t) {
        // ---------------- layer 0: whh0 quarters q0..q3 ----------------
        ACC_INIT(0); XPART;
        LOADQ(0, 0, 1, RA0, RA1);                 // S(q2)
        GATE_HI(0, 0, 0);                         // q0
        __syncthreads();                          // F1
        LOADQ(0, 1, 1, RB0, RB1);                 // S(q3)
        GATE_HI(0, 1, 1);                         // q1
        COMMITQ(RA0, RA1, 0);                     // C(q2)
        __syncthreads();                          // F2
        LOADQ(1, 0, 0, RA0, RA1);                 // S(q4)
        GATE_LO(0, 0, 0);                         // q2
        COMMITQ(RB0, RB1, 1);                     // C(q3)
        __syncthreads();                          // F3
        LOADQ(1, 1, 0, RB0, RB1);                 // S(q5)
        GATE_LO(0, 1, 1);                         // q3
        COMMITQ(RA0, RA1, 0);                     // C(q4)
        __syncthreads();                          // F4
        CELLW(0, c0);                             // h0 -> plane0 (pause phase)
        __syncthreads();                          // F5
        // ---------------- layer 1: wih1 q4..q7, whh1 q8..q11 ----------------
        ACC_INIT(1);
        LOADQ(1, 0, 1, RA0, RA1);                 // S(q6)
        GATE_HI(0, 0, 0);                         // q4 (A=h0 new)
        COMMITQ(RB0, RB1, 1);                     // C(q5)
        __syncthreads();                          // F6
        LOADQ(1, 1, 1, RB0, RB1);                 // S(q7)
        GATE_HI(0, 1, 1);                         // q5
        COMMITQ(RA0, RA1, 0);                     // C(q6)
        __syncthreads();                          // F7
        LOADQ(2, 0, 0, RA0, RA1);                 // S(q8)
        GATE_LO(0, 0, 0);                         // q6
        COMMITQ(RB0, RB1, 1);                     // C(q7)
        __syncthreads();                          // F8
        LOADQ(2, 1, 0, RB0, RB1);                 // S(q9)
        GATE_LO(0, 1, 1);                         // q7
        COMMITQ(RA0, RA1, 0);                     // C(q8)
        __syncthreads();                          // F9
        LOADQ(2, 0, 1, RA0, RA1);                 // S(q10)
        GATE_HI(1, 0, 0);                         // q8 (A=h1 old)
        COMMITQ(RB0, RB1, 1);                     // C(q9)
        __syncthreads();                          // F10
        LOADQ(2, 1, 1, RB0, RB1);                 // S(q11)
        GATE_HI(1, 1, 1);                         // q9
        COMMITQ(RA0, RA1, 0);                     // C(q10)
        __syncthreads();                          // F11
        LOADQ(3, 0, 0, RA0, RA1);                 // S(q12)
        GATE_LO(1, 0, 0);                         // q10
        COMMITQ(RB0, RB1, 1);                     // C(q11)
        __syncthreads();                          // F12
        LOADQ(3, 1, 0, RB0, RB1);                 // S(q13)
        GATE_LO(1, 1, 1);                         // q11
        COMMITQ(RA0, RA1, 0);                     // C(q12)
        __syncthreads();                          // F13
        CELLW(1, c1);                             // h1 -> plane1 (pause)
        __syncthreads();                          // F14
        // ---------------- layer 2: wih2 q12..q15, whh2 q16..q19 ----------------
        ACC_INIT(2);
        LOADQ(3, 0, 1, RA0, RA1);                 // S(q14)
        GATE_HI(1, 0, 0);                         // q12 (A=h1 new)
        COMMITQ(RB0, RB1, 1);                     // C(q13)
        __syncthreads();                          // F15
        LOADQ(3, 1, 1, RB0, RB1);                 // S(q15)
        GATE_HI(1, 1, 1);                         // q13
        COMMITQ(RA0, RA1, 0);                     // C(q14)
        __syncthreads();                          // F16
        LOADQ(4, 0, 0, RA0, RA1);                 // S(q16)
        GATE_LO(1, 0, 0);                         // q14
        COMMITQ(RB0, RB1, 1);                     // C(q15)
        __syncthreads();                          // F17
        LOADQ(4, 1, 0, RB0, RB1);                 // S(q17)
        GATE_LO(1, 1, 1);                         // q15
        COMMITQ(RA0, RA1, 0);                     // C(q16)
        __syncthreads();                          // F18
        LOADQ(4, 0, 1, RA0, RA1);                 // S(q18)
        GATE_HI(2, 0, 0);                         // q16 (A=h2 old)
        COMMITQ(RB0, RB1, 1);                     // C(q17)
        __syncthreads();                          // F19
        LOADQ(4, 1, 1, RB0, RB1);                 // S(q19)
        GATE_HI(2, 1, 1);                         // q17
        COMMITQ(RA0, RA1, 0);                     // C(q18)
        __syncthreads();                          // F20
        LOADW1(RA0);                              // S(q20 = w1 frags)
        GATE_LO(2, 0, 0);                         // q18
        COMMITQ(RB0, RB1, 1);                     // C(q19)
        __syncthreads();                          // F21
        GATE_LO(2, 1, 1);                         // q19
        COMMITW1(RA0, 0);                         // C(q20) -> buf0
        __syncthreads();                          // F22
        CELLW(2, c2);                             // h2 -> plane2 (pause)
        __syncthreads();                          // F23
        // ---------------- MLP head (+ next-step warmup through it) ----------------
        LOADQ(0, 0, 0, RA0, RA1);                 // S(q0, next step)
        MLP1;                                     // reads plane2 + buf0(w1), writes Y1
        __syncthreads();                          // F24
        LOADQ(0, 1, 0, RB0, RB1);                 // S(q1, next step)
        MLP2;                                     // Y1 -> Y2
        COMMITQ(RA0, RA1, 0);                     // C(q0)
        __syncthreads();                          // F25
        MLP3_OUT;                                 // Y2 -> XFB + out ring
        COMMITQ(RB0, RB1, 1);                     // C(q1)
        if ((t & 7) == 7) {                       // flush 8 buffered steps
            __syncthreads();
            long tb = t - 7;
            #pragma unroll
            for (int it = 0; it < 6; ++it) {
                int i = it * NTHR + tid;          // 0..3071
                int e = i / 24, j = i - e * 24;
                out[(eg0 + e) * outs + tb * 3 + j] =
                    *(const float*)(lds + OUT_OFF + e * 96 + j * 4);
            }
        }
        __syncthreads();                          // F26 (= F0 of next step)
    }

    // tail flush (T not multiple of 8)
    int nst = T & 7;
    if (nst) {
        int nfl = BT * nst * 3;
        for (int i = tid; i < nfl; i += NTHR) {
            int e = i / (nst * 3), j = i - e * (nst * 3);
            out[(eg0 + e) * outs + (long)(T - nst) * 3 + j] =
                *(const float*)(lds + OUT_OFF + e * 96 + j * 4);
        }
    }
}

extern "C" void kernel_launch(void* const* d_in, const int* in_sizes, int n_in,
                              void* d_out, int out_size, void* d_ws, size_t ws_size,
                              hipStream_t stream)
{
    const float* noise = (const float*)d_in[0];
    const float* wih0  = (const float*)d_in[1];
    const float* whh0  = (const float*)d_in[2];
    const float* bih0  = (const float*)d_in[3];
    const float* bhh0  = (const float*)d_in[4];
    const float* wih1  = (const float*)d_in[5];
    const float* whh1  = (const float*)d_in[6];
    const float* bih1  = (const float*)d_in[7];
    const float* bhh1  = (const float*)d_in[8];
    const float* wih2  = (const float*)d_in[9];
    const float* whh2  = (const float*)d_in[10];
    const float* bih2  = (const float*)d_in[11];
    const float* bhh2  = (const float*)d_in[12];
    const float* w1g   = (const float*)d_in[13];
    const float* b1g   = (const float*)d_in[14];
    const float* w2g   = (const float*)d_in[15];
    const float* b2g   = (const float*)d_in[16];
    const float* w3g   = (const float*)d_in[17];
    const float* b3g   = (const float*)d_in[18];
    const int*   lenp  = (const int*)d_in[19];
    float* out = (float*)d_out;

    int B = in_sizes[0] / 3;              // 32768
    int grid = B / BT;                    // 256 blocks = 1 per CU

    prep_weights<<<82, 256, 0, stream>>>(whh0, wih1, whh1, wih2, whh2, w1g);

    hipFuncSetAttribute((const void*)lstm_mfma,
                        hipFuncAttributeMaxDynamicSharedMemorySize, LDS_TOTAL);
    lstm_mfma<<<grid, NTHR, LDS_TOTAL, stream>>>(
        noise, wih0, whh0, bih0, bhh0, wih1, whh1, bih1, bhh1,
        wih2, whh2, bih2, bhh2, w1g, b1g, w2g, b2g, w3g, b3g, lenp, out);
}

// Round 4
// 6134.012 us; speedup vs baseline: 2.8084x; 1.1035x over previous
//
#include <hip/hip_runtime.h>

typedef __attribute__((ext_vector_type(4))) float  f32x4;
typedef __attribute__((ext_vector_type(8))) short  bf16x8;

#define NTHR 1024
#define BT   128

// ---------------- LDS byte map (total 159632 <= 163840) ----------------
// planes: [layer][split] 16384B each: [128 elems][64 units] bf16, XOR-swizzled
#define PLANE(L,S) ((L)*32768 + (S)*16384)
#define QBUFP(p)   (98304 + ((p)<<14))     // 2 parity-rotating 16KB stage buffers
#define XFB_OFF    131072                  // [128][3] f32 feedback x (1536B)
#define Y1_OFF     132608                  // [128][34] bf16 (8704B)
#define Y2_OFF     141312                  // [128][18] bf16 (4608B)
#define W2L_OFF    145920                  // [16][32] bf16 (1024B)
#define BGL_OFF    146944                  // [3][256] f32 bias sums (3072B)
#define B1L_OFF    150016                  // [32] f32
#define B2L_OFF    150144                  // [16] f32
#define B3L_OFF    150208                  // [4] f32
#define W3L_OFF    150224                  // [3][16] f32 (192B)
#define W0L_OFF    150416                  // [256][3] f32 (3072B)
#define OUT_OFF    153488                  // [128][12] f32 out ring (6144B)
#define LDS_TOTAL  159632

// frag-ordered split weights: 5 gate mats * 64KB + w1 8KB
__device__ __align__(16) unsigned char g_wsbuf[335872];

__device__ __forceinline__ unsigned short f2bf(float v) {
    unsigned int x = __float_as_uint(v);
    unsigned int r = x + 0x7fffu + ((x >> 16) & 1u);
    return (unsigned short)(r >> 16);
}
__device__ __forceinline__ float bf2f_lo(unsigned int d) { return __uint_as_float(d << 16); }
__device__ __forceinline__ float bf2f_hi(unsigned int d) { return __uint_as_float(d & 0xffff0000u); }

__device__ __forceinline__ float fsig(float x) {
    return __builtin_amdgcn_rcpf(1.0f + __expf(-x));
}
__device__ __forceinline__ float ftanh(float x) {
    float e = __expf(2.0f * x);
    return 1.0f - 2.0f * __builtin_amdgcn_rcpf(e + 1.0f);
}

// ---------------- prologue: frag-order + split weights (unchanged layout) ----------------
__global__ void prep_weights(const float* __restrict__ whh0, const float* __restrict__ wih1,
                             const float* __restrict__ whh1, const float* __restrict__ wih2,
                             const float* __restrict__ whh2, const float* __restrict__ w1g)
{
    int gi = blockIdx.x * 256 + threadIdx.x;
    if (gi < 20480) {
        int m = gi >> 12;
        int rem = gi & 4095;
        int b = rem >> 6, l = rem & 63;
        int s = b & 1, ks = (b >> 1) & 1, g = (b >> 2) & 3, ug = b >> 4;
        int row = g * 64 + ug * 16 + (l & 15);
        int kb  = ks * 32 + (l >> 4) * 8;
        const float* src = (m == 0) ? whh0 : (m == 1) ? wih1 : (m == 2) ? whh1
                         : (m == 3) ? wih2 : whh2;
        unsigned short o[8];
        #pragma unroll
        for (int i = 0; i < 8; ++i) {
            float v = src[row * 64 + kb + i];
            unsigned short hh = f2bf(v);
            if (s) {
                float r2 = v - __uint_as_float((unsigned int)hh << 16);
                hh = f2bf(r2);
            }
            o[i] = hh;
        }
        unsigned char* dst = g_wsbuf + m * 65536 + b * 1024 + l * 16;
        #pragma unroll
        for (int i = 0; i < 8; ++i) ((unsigned short*)dst)[i] = o[i];
    } else if (gi < 20992) {
        int g2 = gi - 20480;
        int b = g2 >> 6, l = g2 & 63;
        int s = b & 1, ks = (b >> 1) & 1, nt = b >> 2;
        int row = nt * 16 + (l & 15);
        int kb  = ks * 32 + (l >> 4) * 8;
        unsigned short o[8];
        #pragma unroll
        for (int i = 0; i < 8; ++i) {
            float v = w1g[row * 64 + kb + i];
            unsigned short hh = f2bf(v);
            if (s) {
                float r2 = v - __uint_as_float((unsigned int)hh << 16);
                hh = f2bf(r2);
            }
            o[i] = hh;
        }
        unsigned char* dst = g_wsbuf + 327680 + b * 1024 + l * 16;
        #pragma unroll
        for (int i = 0; i < 8; ++i) ((unsigned short*)dst)[i] = o[i];
    }
}

#define MFMA_(A,B,C) __builtin_amdgcn_mfma_f32_16x16x32_bf16(A, B, C, 0, 0, 0)

// 1024-thread staging: one dwordx4 per thread per 16KB quarter.
// frag-block b = fragblk*4 + ks*2 + s ; thread covers fragblk = tid>>6.
#define LOADQ(m, ks, s, R) \
    R = *(const bf16x8*)(g_wsbuf + (m) * 65536 + \
        (((tid >> 6) * 4 + (ks) * 2 + (s))) * 1024 + (tid & 63) * 16)
#define COMMITQ(R, p) \
    *(bf16x8*)(lds + QBUFP(p) + tid * 16) = R
#define LOADW1(R) do { if (tid < 512) \
    R = *(const bf16x8*)(g_wsbuf + 327680 + (tid >> 6) * 1024 + (tid & 63) * 16); } while (0)
#define COMMITW1(R, p) do { if (tid < 512) \
    *(bf16x8*)(lds + QBUFP(p) + tid * 16) = R; } while (0)

#define ACC_INIT(L) do { \
    _Pragma("unroll") for (int g_ = 0; g_ < 4; ++g_) { \
        float b_ = *(const float*)(lds + BGL_OFF + ((L) * 256 + g_ * 64 + u) * 4); \
        f32x4 t_ = {b_, b_, b_, b_}; \
        _Pragma("unroll") for (int mt_ = 0; mt_ < 2; ++mt_) acc[g_][mt_] = t_; \
    } } while (0)

#define GATE_HI(APL, ks, P) do { \
    bf16x8 bh_[4]; \
    _Pragma("unroll") for (int g_ = 0; g_ < 4; ++g_) \
        bh_[g_] = *(const bf16x8*)(lds + QBUFP(P) + (ug * 4 + g_) * 1024 + lane * 16); \
    _Pragma("unroll") for (int mt_ = 0; mt_ < 2; ++mt_) { \
        int ab_ = (((mbase + mt_ * 16 + l15) * 128 + (ks) * 64 + l4 * 16)) ^ rswz; \
        bf16x8 ah_ = *(const bf16x8*)(lds + PLANE(APL, 0) + ab_); \
        bf16x8 al_ = *(const bf16x8*)(lds + PLANE(APL, 1) + ab_); \
        _Pragma("unroll") for (int g_ = 0; g_ < 4; ++g_) { \
            acc[g_][mt_] = MFMA_(ah_, bh_[g_], acc[g_][mt_]); \
            acc[g_][mt_] = MFMA_(al_, bh_[g_], acc[g_][mt_]); \
        } } } while (0)

#define GATE_LO(APL, ks, P) do { \
    bf16x8 bl_[4]; \
    _Pragma("unroll") for (int g_ = 0; g_ < 4; ++g_) \
        bl_[g_] = *(const bf16x8*)(lds + QBUFP(P) + (ug * 4 + g_) * 1024 + lane * 16); \
    _Pragma("unroll") for (int mt_ = 0; mt_ < 2; ++mt_) { \
        int ab_ = (((mbase + mt_ * 16 + l15) * 128 + (ks) * 64 + l4 * 16)) ^ rswz; \
        bf16x8 ah_ = *(const bf16x8*)(lds + PLANE(APL, 0) + ab_); \
        _Pragma("unroll") for (int g_ = 0; g_ < 4; ++g_) \
            acc[g_][mt_] = MFMA_(ah_, bl_[g_], acc[g_][mt_]); \
    } } while (0)

#define CELLW(L, CARR) do { \
    _Pragma("unroll") for (int mt_ = 0; mt_ < 2; ++mt_) \
    _Pragma("unroll") for (int r_ = 0; r_ < 4; ++r_) { \
        float gi_ = fsig(acc[0][mt_][r_]); \
        float gf_ = fsig(acc[1][mt_][r_]); \
        float gg_ = ftanh(acc[2][mt_][r_]); \
        float go_ = fsig(acc[3][mt_][r_]); \
        float cn_ = gf_ * CARR[mt_ * 4 + r_] + gi_ * gg_; \
        CARR[mt_ * 4 + r_] = cn_; \
        float hn_ = go_ * ftanh(cn_); \
        int e_ = mbase + mt_ * 16 + l4 * 4 + r_; \
        int wb_ = ((e_ * 128 + u * 2)) ^ ((e_ & 7) << 4); \
        unsigned short hh_ = f2bf(hn_); \
        float hf_ = __uint_as_float((unsigned int)hh_ << 16); \
        unsigned short hl_ = f2bf(hn_ - hf_); \
        *(unsigned short*)(lds + PLANE(L, 0) + wb_) = hh_; \
        *(unsigned short*)(lds + PLANE(L, 1) + wb_) = hl_; \
    } } while (0)

#define XPART do { \
    _Pragma("unroll") for (int mt_ = 0; mt_ < 2; ++mt_) \
    _Pragma("unroll") for (int r_ = 0; r_ < 4; ++r_) { \
        int e_ = mbase + mt_ * 16 + l4 * 4 + r_; \
        const float* xp_ = (const float*)(lds + XFB_OFF + e_ * 12); \
        float x0_ = xp_[0], x1_ = xp_[1], x2_ = xp_[2]; \
        _Pragma("unroll") for (int g_ = 0; g_ < 4; ++g_) { \
            const float* w0_ = (const float*)(lds + W0L_OFF + (g_ * 64 + u) * 12); \
            acc[g_][mt_][r_] += x0_ * w0_[0] + x1_ * w0_[1] + x2_ * w0_[2]; \
        } } } while (0)

#define MLP1(P) do { \
    int Mt_ = wv >> 1, half_ = wv & 1; \
    float b1_ = *(const float*)(lds + B1L_OFF + (half_ * 16 + l15) * 4); \
    f32x4 a1_ = {b1_, b1_, b1_, b1_}; \
    _Pragma("unroll") for (int ks_ = 0; ks_ < 2; ++ks_) { \
        int ab_ = (((Mt_ * 16 + l15) * 128 + ks_ * 64 + l4 * 16)) ^ rswz; \
        bf16x8 ah_ = *(const bf16x8*)(lds + PLANE(2, 0) + ab_); \
        bf16x8 al_ = *(const bf16x8*)(lds + PLANE(2, 1) + ab_); \
        bf16x8 wh_ = *(const bf16x8*)(lds + QBUFP(P) + ((half_ * 2 + ks_) * 2 + 0) * 1024 + lane * 16); \
        bf16x8 wl_ = *(const bf16x8*)(lds + QBUFP(P) + ((half_ * 2 + ks_) * 2 + 1) * 1024 + lane * 16); \
        a1_ = MFMA_(ah_, wh_, a1_); \
        a1_ = MFMA_(al_, wh_, a1_); \
        a1_ = MFMA_(ah_, wl_, a1_); \
    } \
    _Pragma("unroll") for (int r_ = 0; r_ < 4; ++r_) { \
        float y_ = a1_[r_]; y_ = (y_ >= 0.f) ? y_ : 0.01f * y_; \
        int e_ = Mt_ * 16 + l4 * 4 + r_; \
        *(unsigned short*)(lds + Y1_OFF + e_ * 68 + half_ * 32 + l15 * 2) = f2bf(y_); \
    } } while (0)

#define MLP2 do { \
    int e2_ = tid & 127, rg_ = tid >> 7; \
    float a2_[2]; \
    _Pragma("unroll") for (int m_ = 0; m_ < 2; ++m_) \
        a2_[m_] = *(const float*)(lds + B2L_OFF + (rg_ * 2 + m_) * 4); \
    _Pragma("unroll") for (int kd_ = 0; kd_ < 16; ++kd_) { \
        unsigned int d_ = *(const unsigned int*)(lds + Y1_OFF + e2_ * 68 + kd_ * 4); \
        float v0_ = bf2f_lo(d_), v1_ = bf2f_hi(d_); \
        _Pragma("unroll") for (int m_ = 0; m_ < 2; ++m_) { \
            unsigned int w_ = *(const unsigned int*)(lds + W2L_OFF + ((rg_ * 2 + m_) * 32 + kd_ * 2) * 2); \
            a2_[m_] = fmaf(v0_, bf2f_lo(w_), a2_[m_]); \
            a2_[m_] = fmaf(v1_, bf2f_hi(w_), a2_[m_]); \
        } } \
    _Pragma("unroll") for (int m_ = 0; m_ < 2; ++m_) { \
        float y_ = a2_[m_]; y_ = (y_ >= 0.f) ? y_ : 0.01f * y_; \
        *(unsigned short*)(lds + Y2_OFF + e2_ * 36 + (rg_ * 2 + m_) * 2) = f2bf(y_); \
    } } while (0)

#define MLP3_OUT do { \
    if (tid < 384) { \
        int e3_ = tid & 127, r3_ = tid >> 7; \
        float a3_ = *(const float*)(lds + B3L_OFF + r3_ * 4); \
        _Pragma("unroll") for (int kd_ = 0; kd_ < 8; ++kd_) { \
            unsigned int d_ = *(const unsigned int*)(lds + Y2_OFF + e3_ * 36 + kd_ * 4); \
            a3_ = fmaf(bf2f_lo(d_), *(const float*)(lds + W3L_OFF + (r3_ * 16 + kd_ * 2) * 4),     a3_); \
            a3_ = fmaf(bf2f_hi(d_), *(const float*)(lds + W3L_OFF + (r3_ * 16 + kd_ * 2 + 1) * 4), a3_); \
        } \
        float y_ = (a3_ >= 0.f) ? a3_ : 0.01f * a3_; \
        *(float*)(lds + XFB_OFF + e3_ * 12 + r3_ * 4) = y_; \
        *(float*)(lds + OUT_OFF + e3_ * 48 + (t & 3) * 12 + r3_ * 4) = y_; \
    } } while (0)

// ---------------- main persistent kernel ----------------
extern "C" __global__ void __launch_bounds__(NTHR, 4)
lstm_mfma(const float* __restrict__ noise,
          const float* __restrict__ wih0, const float* __restrict__ whh0,
          const float* __restrict__ bih0, const float* __restrict__ bhh0,
          const float* __restrict__ wih1, const float* __restrict__ whh1,
          const float* __restrict__ bih1, const float* __restrict__ bhh1,
          const float* __restrict__ wih2, const float* __restrict__ whh2,
          const float* __restrict__ bih2, const float* __restrict__ bhh2,
          const float* __restrict__ w1g, const float* __restrict__ b1g,
          const float* __restrict__ w2g, const float* __restrict__ b2g,
          const float* __restrict__ w3g, const float* __restrict__ b3g,
          const int* __restrict__ lenp, float* __restrict__ out)
{
    extern __shared__ unsigned char lds[];
    const int tid  = threadIdx.x;
    const int lane = tid & 63;
    const int wv   = tid >> 6;       // wave 0..15
    const int ug   = wv & 3;         // unit group (16 units)
    const int mh   = wv >> 2;        // M quarter 0..3
    const int l15  = lane & 15;
    const int l4   = lane >> 4;      // k-group
    const int u    = ug * 16 + l15;  // unit 0..63
    const int mbase = mh * 32;
    const int rswz  = (lane & 7) << 4;
    const int T = *lenp;
    const long eg0  = (long)blockIdx.x * BT;
    const long outs = 3L * T;

    // per-thread recurrent c state: 8 (unit,elem) pairs per layer
    float c0[8], c1[8], c2[8];
    #pragma unroll
    for (int i = 0; i < 8; ++i) { c0[i] = 0.f; c1[i] = 0.f; c2[i] = 0.f; }

    // staging registers (3-deep rotation)
    bf16x8 RA, RB, RC;

    // issue warmup loads early (q0,q1,q2)
    LOADQ(0, 0, 0, RA);
    LOADQ(0, 1, 0, RB);
    LOADQ(0, 0, 1, RC);

    // ---- LDS init ----
    for (int i = tid; i < 98304 / 4; i += NTHR) ((unsigned int*)lds)[i] = 0u;  // h planes = 0
    if (tid < BT) {
        #pragma unroll
        for (int k = 0; k < 3; ++k)
            *(float*)(lds + XFB_OFF + tid * 12 + k * 4) = noise[(eg0 + tid) * 3 + k];
    }
    if (tid < 512) *(unsigned short*)(lds + W2L_OFF + tid * 2) = f2bf(w2g[tid]);
    if (tid < 768) {                                   // bias sums
        int l = tid >> 8, r = tid & 255;
        const float* bi = (l == 0) ? bih0 : ((l == 1) ? bih1 : bih2);
        const float* bh = (l == 0) ? bhh0 : ((l == 1) ? bhh1 : bhh2);
        *(float*)(lds + BGL_OFF + tid * 4) = bi[r] + bh[r];
    }
    if (tid < 768) *(float*)(lds + W0L_OFF + tid * 4) = wih0[tid];  // [256][3]
    if (tid < 32) *(float*)(lds + B1L_OFF + tid * 4) = b1g[tid];
    if (tid < 16) *(float*)(lds + B2L_OFF + tid * 4) = b2g[tid];
    if (tid < 3)  *(float*)(lds + B3L_OFF + tid * 4) = b3g[tid];
    if (tid < 48) *(float*)(lds + W3L_OFF + tid * 4) = w3g[tid];

    __syncthreads();                 // init visible
    COMMITQ(RA, 0);                  // q0 -> buf0 (vmcnt auto-waited)
    __syncthreads();                 // buf0 ready

    f32x4 acc[4][2];

    #pragma unroll 1
    for (int t = 0; t < T; ++t) {
        const int bp = t & 1;
        // ---------------- layer 0: whh0 q0..q3 (A = plane0 old) ----------------
        COMMITQ(RB, bp ^ 1); LOADQ(0, 1, 1, RA);      // commit q1, load q3
        ACC_INIT(0); XPART;
        GATE_HI(0, 0, bp);                            // q0
        __syncthreads();
        COMMITQ(RC, bp); LOADQ(1, 0, 0, RB);          // commit q2, load q4
        GATE_HI(0, 1, bp ^ 1);                        // q1
        __syncthreads();
        COMMITQ(RA, bp ^ 1); LOADQ(1, 1, 0, RC);      // commit q3, load q5
        GATE_LO(0, 0, bp);                            // q2
        __syncthreads();
        COMMITQ(RB, bp); LOADQ(1, 0, 1, RA);          // commit q4, load q6
        GATE_LO(0, 1, bp ^ 1);                        // q3
        __syncthreads();
        CELLW(0, c0);                                 // h0 -> plane0
        __syncthreads();
        // ---------------- layer 1: wih1 q4..q7 (A=plane0 new), whh1 q8..q11 (A=plane1 old) ----------------
        COMMITQ(RC, bp ^ 1); LOADQ(1, 1, 1, RB);      // commit q5, load q7
        ACC_INIT(1);
        GATE_HI(0, 0, bp);                            // q4
        __syncthreads();
        COMMITQ(RA, bp); LOADQ(2, 0, 0, RC);          // commit q6, load q8
        GATE_HI(0, 1, bp ^ 1);                        // q5
        __syncthreads();
        COMMITQ(RB, bp ^ 1); LOADQ(2, 1, 0, RA);      // commit q7, load q9
        GATE_LO(0, 0, bp);                            // q6
        __syncthreads();
        COMMITQ(RC, bp); LOADQ(2, 0, 1, RB);          // commit q8, load q10
        GATE_LO(0, 1, bp ^ 1);                        // q7
        __syncthreads();
        COMMITQ(RA, bp ^ 1); LOADQ(2, 1, 1, RC);      // commit q9, load q11
        GATE_HI(1, 0, bp);                            // q8
        __syncthreads();
        COMMITQ(RB, bp); LOADQ(3, 0, 0, RA);          // commit q10, load q12
        GATE_HI(1, 1, bp ^ 1);                        // q9
        __syncthreads();
        COMMITQ(RC, bp ^ 1); LOADQ(3, 1, 0, RB);      // commit q11, load q13
        GATE_LO(1, 0, bp);                            // q10
        __syncthreads();
        COMMITQ(RA, bp); LOADQ(3, 0, 1, RC);          // commit q12, load q14
        GATE_LO(1, 1, bp ^ 1);                        // q11
        __syncthreads();
        CELLW(1, c1);                                 // h1 -> plane1
        __syncthreads();
        // ---------------- layer 2: wih2 q12..q15 (A=plane1 new), whh2 q16..q19 (A=plane2 old) ----------------
        COMMITQ(RB, bp ^ 1); LOADQ(3, 1, 1, RA);      // commit q13, load q15
        ACC_INIT(2);
        GATE_HI(1, 0, bp);                            // q12
        __syncthreads();
        COMMITQ(RC, bp); LOADQ(4, 0, 0, RB);          // commit q14, load q16
        GATE_HI(1, 1, bp ^ 1);                        // q13
        __syncthreads();
        COMMITQ(RA, bp ^ 1); LOADQ(4, 1, 0, RC);      // commit q15, load q17
        GATE_LO(1, 0, bp);                            // q14
        __syncthreads();
        COMMITQ(RB, bp); LOADQ(4, 0, 1, RA);          // commit q16, load q18
        GATE_LO(1, 1, bp ^ 1);                        // q15
        __syncthreads();
        COMMITQ(RC, bp ^ 1); LOADQ(4, 1, 1, RB);      // commit q17, load q19
        GATE_HI(2, 0, bp);                            // q16
        __syncthreads();
        COMMITQ(RA, bp); LOADW1(RC);                  // commit q18, load q20 (w1)
        GATE_HI(2, 1, bp ^ 1);                        // q17
        __syncthreads();
        COMMITQ(RB, bp ^ 1); LOADQ(0, 0, 0, RA);      // commit q19, load q0'
        GATE_LO(2, 0, bp);                            // q18
        __syncthreads();
        COMMITW1(RC, bp); LOADQ(0, 1, 0, RB);         // commit q20(w1), load q1'
        GATE_LO(2, 1, bp ^ 1);                        // q19
        __syncthreads();
        CELLW(2, c2);                                 // h2 -> plane2
        __syncthreads();
        // ---------------- MLP head ----------------
        COMMITQ(RA, bp ^ 1); LOADQ(0, 0, 1, RC);      // commit q0', load q2'
        MLP1(bp);                                     // y1 via MFMA (A=plane2, B=w1)
        __syncthreads();
        MLP2;                                         // y1 -> y2 (VALU)
        __syncthreads();
        MLP3_OUT;                                     // y2 -> XFB + out ring
        if ((t & 3) == 3) {                           // flush 4 buffered steps
            __syncthreads();
            long tb = t - 3;
            for (int i = tid; i < 1536; i += NTHR) {
                int e = i / 12, j = i - e * 12;
                out[(eg0 + e) * outs + tb * 3 + j] =
                    *(const float*)(lds + OUT_OFF + e * 48 + j * 4);
            }
        }
        __syncthreads();                              // step boundary
    }

    // tail flush (T not multiple of 4)
    int nst = T & 3;
    if (nst) {
        int nfl = BT * nst * 3;
        for (int i = tid; i < nfl; i += NTHR) {
            int e = i / (nst * 3), j = i - e * (nst * 3);
            out[(eg0 + e) * outs + (long)(T - nst) * 3 + j] =
                *(const float*)(lds + OUT_OFF + e * 48 + j * 4);
        }
    }
}

extern "C" void kernel_launch(void* const* d_in, const int* in_sizes, int n_in,
                              void* d_out, int out_size, void* d_ws, size_t ws_size,
                              hipStream_t stream)
{
    const float* noise = (const float*)d_in[0];
    const float* wih0  = (const float*)d_in[1];
    const float* whh0  = (const float*)d_in[2];
    const float* bih0  = (const float*)d_in[3];
    const float* bhh0  = (const float*)d_in[4];
    const float* wih1  = (const float*)d_in[5];
    const float* whh1  = (const float*)d_in[6];
    const float* bih1  = (const float*)d_in[7];
    const float* bhh1  = (const float*)d_in[8];
    const float* wih2  = (const float*)d_in[9];
    const float* whh2  = (const float*)d_in[10];
    const float* bih2  = (const float*)d_in[11];
    const float* bhh2  = (const float*)d_in[12];
    const float* w1g   = (const float*)d_in[13];
    const float* b1g   = (const float*)d_in[14];
    const float* w2g   = (const float*)d_in[15];
    const float* b2g   = (const float*)d_in[16];
    const float* w3g   = (const float*)d_in[17];
    const float* b3g   = (const float*)d_in[18];
    const int*   lenp  = (const int*)d_in[19];
    float* out = (float*)d_out;

    int B = in_sizes[0] / 3;              // 32768
    int grid = B / BT;                    // 256 blocks = 1 per CU

    prep_weights<<<82, 256, 0, stream>>>(whh0, wih1, whh1, wih2, whh2, w1g);

    hipFuncSetAttribute((const void*)lstm_mfma,
                        hipFuncAttributeMaxDynamicSharedMemorySize, LDS_TOTAL);
    lstm_mfma<<<grid, NTHR, LDS_TOTAL, stream>>>(
        noise, wih0, whh0, bih0, bhh0, wih1, whh1, bih1, bhh1,
        wih2, whh2, bih2, bhh2, w1g, b1g, w2g, b2g, w3g, b3g, lenp, out);
}